// Round 18
// baseline (173.436 us; speedup 1.0000x reference)
//
#include <hip/hip_runtime.h>
#include <cmath>
#include <cstddef>

// Shapes (fixed): U=2048, B=4, D=512, NHEAD=8, dh=64, R=S=M=64
// Q = KV = 2176, rows = 8704
#define QLEN 2176
#define NROWS 8704
#define NEG_INF_V -100000000.0f
#define NBITW (4 * QLEN * 68)   // per-b bitmask words

#define CANON_BLKS 2312         // NBITW / 256
#define CONV_BLKS  2176         // per conv target (kv / q)
#define TRANS_BLKS 1024         // 64 x 16

typedef __attribute__((ext_vector_type(8))) short short8;
typedef __attribute__((ext_vector_type(4))) float f32x4;
typedef __attribute__((ext_vector_type(16))) float f32x16;
typedef unsigned short ushort_t;

#define MFMA16(A, B, C) __builtin_amdgcn_mfma_f32_16x16x32_bf16(A, B, C, 0, 0, 0)
#define MFMA32(A, B, C) __builtin_amdgcn_mfma_f32_32x32x16_bf16(A, B, C, 0, 0, 0)

#if __has_builtin(__builtin_amdgcn_exp2f)
#define EXP2(x) __builtin_amdgcn_exp2f(x)
#else
#define EXP2(x) __expf((x) * 0.6931471805599453f)
#endif

__device__ __forceinline__ ushort_t f2bf(float f) {
    unsigned int u = __builtin_bit_cast(unsigned int, f);
    u += 0x7FFFu + ((u >> 16) & 1u);   // RNE
    return (ushort_t)(u >> 16);
}

__device__ __forceinline__ unsigned int cvtpk_bf16(float lo, float hi) {
    unsigned int r;
    asm volatile("v_cvt_pk_bf16_f32 %0, %1, %2" : "=v"(r) : "v"(lo), "v"(hi));
    return r;
}

// async global->LDS, 16B per lane; dst must be the wave-uniform chunk base
__device__ __forceinline__ void gload16(const void* g, void* l) {
    __builtin_amdgcn_global_load_lds(
        (const __attribute__((address_space(1))) void*)g,
        (__attribute__((address_space(3))) void*)l, 16, 0, 0);
}

// ---------------- fused prep: canon | conv kv | conv q | weight transpose ------------
// block ranges: [0,2312) canon, [2312,4488) conv kvin, [4488,6664) conv qin,
// [6664,7688) transpose weights.
__global__ __launch_bounds__(256) void prep_kernel(
    const void* __restrict__ mraw, const int* __restrict__ lengths,
    unsigned int* __restrict__ bits,
    const float* __restrict__ memory, const float* __restrict__ right_context,
    const float* __restrict__ utterance, const float* __restrict__ summary,
    ushort_t* __restrict__ kvin, ushort_t* __restrict__ qin,
    const float* __restrict__ w_q, const float* __restrict__ w_kv,
    const float* __restrict__ w_out,
    ushort_t* __restrict__ wtq, ushort_t* __restrict__ wtkv, ushort_t* __restrict__ wtout)
{
    __shared__ float t[32][33];
    const int bx = blockIdx.x;
    if (bx < CANON_BLKS) {
        // inline mask-dtype detect (wave-level ballot over 4KB sample, no barrier)
        const unsigned int* mw = (const unsigned int*)mraw;
        unsigned int a123 = 0, a01 = 0, a23 = 0;
        #pragma unroll
        for (int i = 0; i < 16; ++i) {
            unsigned int wv = mw[(threadIdx.x & 63) * 16 + i];
            a123 |= wv & 0xFFFFFF00u;
            a01  |= wv & 0x0000FFFFu;
            a23  |= wv & 0xFFFF0000u;
        }
        int f;
        if (__ballot(a123 != 0) == 0)                                 f = 0;
        else if (__ballot(a01 != 0) == 0 && __ballot(a23 != 0) != 0)  f = 2;
        else                                                          f = 1;

        int idx = bx * 256 + threadIdx.x;
        if (idx >= NBITW) return;
        int b = idx / (QLEN * 68);
        int rem = idx - b * (QLEN * 68);
        int q = rem / 68, w = rem - q * 68;
        int kv0 = w * 32;
        unsigned int out = 0;
        if (f == 1) {
            const uint4* p = (const uint4*)((const unsigned char*)mraw + (size_t)q * QLEN + kv0);
            uint4 va = p[0], vb = p[1];
            unsigned int ws2[8] = {va.x, va.y, va.z, va.w, vb.x, vb.y, vb.z, vb.w};
            #pragma unroll
            for (int ww = 0; ww < 8; ++ww) {
                unsigned int x = ws2[ww];
                #pragma unroll
                for (int j = 0; j < 4; ++j)
                    out |= ((x >> (8 * j)) & 0xFFu) ? (1u << (ww * 4 + j)) : 0u;
            }
        } else {
            const uint4* p = (const uint4*)((const unsigned int*)mraw + (size_t)q * QLEN + kv0);
            #pragma unroll
            for (int g2 = 0; g2 < 8; ++g2) {
                uint4 v = p[g2];
                out |= (v.x ? 1u : 0u) << (g2 * 4);
                out |= (v.y ? 2u : 0u) << (g2 * 4);
                out |= (v.z ? 4u : 0u) << (g2 * 4);
                out |= (v.w ? 8u : 0u) << (g2 * 4);
            }
        }
        int n = (128 + lengths[b]) - kv0;   // pad: kv >= 128+lengths[b] -> masked
        unsigned int pm = (n <= 0) ? 0xFFFFFFFFu : (n >= 32 ? 0u : (0xFFFFFFFFu << n));
        bits[idx] = out | pm;
    } else if (bx < CANON_BLKS + 2 * CONV_BLKS) {
        // conv-concat f32 -> bf16; kv: [memory, right_context, utterance],
        // q: [right_context, utterance, summary]
        const bool isKV = bx < CANON_BLKS + CONV_BLKS;
        int c = (bx - (isKV ? CANON_BLKS : CANON_BLKS + CONV_BLKS)) * 256 + threadIdx.x;
        int row = c >> 6, ch = c & 63;
        if (row >= NROWS) return;
        const float* src;
        if (isKV) {
            if (row < 256)      src = memory + (size_t)row * 512;
            else if (row < 512) src = right_context + (size_t)(row - 256) * 512;
            else                src = utterance + (size_t)(row - 512) * 512;
        } else {
            if (row < 256)       src = right_context + (size_t)row * 512;
            else if (row < 8448) src = utterance + (size_t)(row - 256) * 512;
            else                 src = summary + (size_t)(row - 8448) * 512;
        }
        float4 v0 = *(const float4*)(src + ch * 8);
        float4 v1 = *(const float4*)(src + ch * 8 + 4);
        short8 o;
        o[0] = (short)f2bf(v0.x); o[1] = (short)f2bf(v0.y);
        o[2] = (short)f2bf(v0.z); o[3] = (short)f2bf(v0.w);
        o[4] = (short)f2bf(v1.x); o[5] = (short)f2bf(v1.y);
        o[6] = (short)f2bf(v1.z); o[7] = (short)f2bf(v1.w);
        ushort_t* dst = isKV ? kvin : qin;
        *(short8*)(dst + (size_t)row * 512 + ch * 8) = o;
    } else {
        // weight transpose [512][N] f32 -> [N][512] bf16
        int idx = bx - (CANON_BLKS + 2 * CONV_BLKS);
        int xb = idx & 63, yb = idx >> 6;
        const float* W; ushort_t* Wt; int N, nb;
        if (xb < 16)      { W = w_q;   Wt = wtq;   N = 512;  nb = xb; }
        else if (xb < 48) { W = w_kv;  Wt = wtkv;  N = 1024; nb = xb - 16; }
        else              { W = w_out; Wt = wtout; N = 512;  nb = xb - 48; }
        int n0 = nb * 32, k0 = yb * 32;
        int tx = threadIdx.x & 31, ty = threadIdx.x >> 5;
        #pragma unroll
        for (int i = 0; i < 4; ++i)
            t[ty + 8 * i][tx] = W[(size_t)(k0 + ty + 8 * i) * N + n0 + tx];
        __syncthreads();
        #pragma unroll
        for (int i = 0; i < 4; ++i)
            Wt[(size_t)(n0 + ty + 8 * i) * 512 + k0 + tx] = f2bf(t[tx][ty + 8 * i]);
    }
}

// ---------------- unified projection GEMM (Q + KV, uniform gload_lds A-path) ---------
// grid (68, 12): bm fastest (weight-panel L2 sharing — r15 A/B). BK=64 (r17: -2.2 us).
__global__ __launch_bounds__(256) void proj_mfma(
    const ushort_t* __restrict__ qin, const ushort_t* __restrict__ kvin,
    const ushort_t* __restrict__ wtq, const ushort_t* __restrict__ wtkv,
    const float* __restrict__ b_q, const float* __restrict__ b_kv, float qscale,
    ushort_t* __restrict__ q_attn, ushort_t* __restrict__ k_attn, ushort_t* __restrict__ v_attn)
{
    __shared__ __align__(16) ushort_t As[128][64];
    __shared__ __align__(16) ushort_t Bs[128][64];
    const int tid = threadIdx.x;
    const int wid = tid >> 6, lane = tid & 63, lr = lane & 15, lg = lane >> 4;
    const int wm = wid >> 1, wn = wid & 1;
    const int bm = blockIdx.x;
    const bool isQ = (blockIdx.y < 4);
    const int bn = isQ ? blockIdx.y : blockIdx.y - 4;
    const ushort_t* A  = isQ ? qin : kvin;
    const ushort_t* Bt = isQ ? wtq : wtkv;
    const float* bias  = isQ ? b_q : b_kv;
    const float scale  = isQ ? qscale : 1.0f;

    f32x4 acc[4][4] = {};

    for (int k0 = 0; k0 < 512; k0 += 64) {
        __syncthreads();
        #pragma unroll
        for (int i = 0; i < 4; ++i) {
            const int q = wid * 256 + 64 * i + lane;   // chunk id 0..1023
            const int row = q >> 3, pc = q & 7;
            const int sc = pc ^ (row & 7);             // content chunk at physical pc
            gload16(A + (size_t)(bm * 128 + row) * 512 + k0 + sc * 8,
                    (ushort_t*)As + (size_t)(wid * 256 + 64 * i) * 8);
            gload16(Bt + (size_t)(bn * 128 + row) * 512 + k0 + sc * 8,
                    (ushort_t*)Bs + (size_t)(wid * 256 + 64 * i) * 8);
        }
        __syncthreads();
        #pragma unroll
        for (int kk = 0; kk < 2; ++kk) {
            short8 af[4], bf[4];
            #pragma unroll
            for (int i = 0; i < 4; ++i) {
                const int ra = wm * 64 + i * 16 + lr;
                const int rb = wn * 64 + i * 16 + lr;
                af[i] = *(const short8*)&As[ra][(((kk * 4 + lg) ^ (ra & 7))) * 8];
                bf[i] = *(const short8*)&Bs[rb][(((kk * 4 + lg) ^ (rb & 7))) * 8];
            }
            #pragma unroll
            for (int i = 0; i < 4; ++i)
                #pragma unroll
                for (int j = 0; j < 4; ++j)
                    acc[i][j] = MFMA16(af[i], bf[j], acc[i][j]);
        }
    }

    // coalesced epilogue: per-wave LDS restage (same values/rounding as scatter)
    __syncthreads();
    const int gcb = bn * 128 + wn * 64;
    ushort_t* dbase; int ccb;
    if (isQ)              { dbase = q_attn; ccb = gcb >> 6; }
    else if (gcb >= 512)  { dbase = v_attn; ccb = (gcb - 512) >> 6; }
    else                  { dbase = k_attn; ccb = gcb >> 6; }
    ushort_t* Wr = ((wid & 2) ? &Bs[0][0] : &As[0][0]) + (wid & 1) * 2048;
    #pragma unroll
    for (int h = 0; h < 2; ++h) {
        #pragma unroll
        for (int ii = 0; ii < 2; ++ii) {
            const int i = h * 2 + ii;
            #pragma unroll
            for (int j = 0; j < 4; ++j) {
                const int colb = j * 16 + lr;
                const float bv = bias[gcb + colb];
                #pragma unroll
                for (int r = 0; r < 4; ++r) {
                    const int rowl = ii * 16 + lg * 4 + r;
                    const int phys = (colb >> 3) ^ (rowl & 7);
                    Wr[rowl * 64 + phys * 8 + (colb & 7)] =
                        f2bf((acc[i][j][r] + bv) * scale);
                }
            }
        }
        const int rl2 = lane >> 1;
        const int gr = bm * 128 + wm * 64 + h * 32 + rl2;
        const int q2 = gr >> 2, b2 = gr & 3;
        ushort_t* drow = dbase + (((size_t)b2 * 8 + ccb) * QLEN + q2) * 64;
        #pragma unroll
        for (int k = 0; k < 4; ++k) {
            const int ch2 = (lane & 1) * 4 + k;
            const int phys = ch2 ^ (rl2 & 7);
            *(short8*)(drow + ch2 * 8) = *(const short8*)&Wr[rl2 * 64 + phys * 8];
        }
    }
}

// ---------------- output projection GEMM + routing epilogue (BK=64) ----------
__global__ __launch_bounds__(256) void gemm_out(
    const ushort_t* __restrict__ A, const ushort_t* __restrict__ Bt,
    const float* __restrict__ bias, float* __restrict__ dstf)
{
    __shared__ __align__(16) ushort_t As[128][64];
    __shared__ __align__(16) ushort_t Bs[128][64];
    const int tid = threadIdx.x;
    const int wid = tid >> 6, lane = tid & 63, lr = lane & 15, lg = lane >> 4;
    const int wm = wid >> 1, wn = wid & 1;
    const int bm = blockIdx.x, bn = blockIdx.y;

    f32x4 acc[4][4] = {};

    for (int k0 = 0; k0 < 512; k0 += 64) {
        __syncthreads();
        #pragma unroll
        for (int i = 0; i < 4; ++i) {
            const int q = wid * 256 + 64 * i + lane;
            const int row = q >> 3, pc = q & 7;
            const int sc = pc ^ (row & 7);
            gload16(A + (size_t)(bm * 128 + row) * 512 + k0 + sc * 8,
                    (ushort_t*)As + (size_t)(wid * 256 + 64 * i) * 8);
            gload16(Bt + (size_t)(bn * 128 + row) * 512 + k0 + sc * 8,
                    (ushort_t*)Bs + (size_t)(wid * 256 + 64 * i) * 8);
        }
        __syncthreads();
        #pragma unroll
        for (int kk = 0; kk < 2; ++kk) {
            short8 af[4], bf[4];
            #pragma unroll
            for (int i = 0; i < 4; ++i) {
                const int ra = wm * 64 + i * 16 + lr;
                const int rb = wn * 64 + i * 16 + lr;
                af[i] = *(const short8*)&As[ra][(((kk * 4 + lg) ^ (ra & 7))) * 8];
                bf[i] = *(const short8*)&Bs[rb][(((kk * 4 + lg) ^ (rb & 7))) * 8];
            }
            #pragma unroll
            for (int i = 0; i < 4; ++i)
                #pragma unroll
                for (int j = 0; j < 4; ++j)
                    acc[i][j] = MFMA16(af[i], bf[j], acc[i][j]);
        }
    }

    #pragma unroll
    for (int i = 0; i < 4; ++i) {
        #pragma unroll
        for (int j = 0; j < 4; ++j) {
            int gc = bn * 128 + wn * 64 + j * 16 + lr;
            float bv = bias[gc];
            #pragma unroll
            for (int r = 0; r < 4; ++r) {
                int gr = bm * 128 + wm * 64 + i * 16 + lg * 4 + r;
                float v = acc[i][j][r] + bv;
                int q = gr >> 2, bb = gr & 3;
                if (q < 2112) {
                    dstf[(size_t)gr * 512 + gc] = v;
                } else if (q < 2175) {
                    float cv = fminf(10.0f, fmaxf(-10.0f, v));
                    dstf[(size_t)2112 * 4 * 512 + ((size_t)(q - 2112) * 4 + bb) * 512 + gc] = cv;
                } // q == 2175 dropped
            }
        }
    }
}

// ---------------- Flash attention: r8 math, KVBLK=128 (single-variable experiment) ----
// Controlled change vs the frozen r8 kernel: stage 128 KV rows per round -> barriers
// 68 -> 34. No prefetch regs (r6 lesson), compile-time bounds (r10 lesson), same LDS
// read layout (r13 lesson). Inner body executed for sub=0,1 in the original kt order
// (kt = 2*kt2+sub) -> bit-identical accumulation. LDS 36 KB (4 blocks/CU, grid needs 2).
__global__ __launch_bounds__(256) void attn_mfma32(
    const ushort_t* __restrict__ Qa, const ushort_t* __restrict__ Ka,
    const ushort_t* __restrict__ Va,
    const unsigned int* __restrict__ mbits,   // [4][2176][68]
    ushort_t* __restrict__ attnb)             // [q*4+b][512] bf16
{
    __shared__ __align__(16) ushort_t Ks[128][72];     // [kv][dh]
    __shared__ __align__(16) ushort_t Vt[2][64][72];   // [sub][dh][kv]

    // XCD-aware swizzle: 544 % 8 == 0 -> bijective
    const int swz = (blockIdx.x & 7) * 68 + (blockIdx.x >> 3);
    const int qt = swz % 17, bh = swz / 17;
    const int b = bh >> 3, h = bh & 7;
    const int tid = threadIdx.x;
    const int w = tid >> 6, lane = tid & 63;
    const int ql = lane & 31, hi = lane >> 5;
    const size_t hb = (size_t)bh * QLEN * 64;
    const int qrow = qt * 128 + w * 32 + ql;

    short8 bq[4];
    #pragma unroll
    for (int m = 0; m < 4; ++m)
        bq[m] = *(const short8*)(Qa + hb + (size_t)qrow * 64 + m * 16 + hi * 8);

    const unsigned int* mrow = mbits + ((size_t)b * QLEN + qrow) * 68;

    f32x16 oacc[2] = {};
    float lsum16[16];
    #pragma unroll
    for (int r = 0; r < 16; ++r) lsum16[r] = 0.0f;

    for (int kt2 = 0; kt2 < 17; ++kt2) {
        const int k0 = kt2 * 128;
        __syncthreads();   // previous round's reads of Ks/Vt done
        // stage K [128][dh]
        #pragma unroll
        for (int p2 = 0; p2 < 4; ++p2) {
            int c = p2 * 256 + tid;
            int row = c >> 3, ch = c & 7;
            *(short8*)&Ks[row][ch * 8] =
                *(const short8*)(Ka + hb + (size_t)(k0 + row) * 64 + ch * 8);
        }
        // stage V transposed [sub][dh][kv]
        #pragma unroll
        for (int p2 = 0; p2 < 4; ++p2) {
            int c = p2 * 256 + tid;
            int kv = c & 127, ch = c >> 7;
            short8 v = *(const short8*)(Va + hb + (size_t)(k0 + kv) * 64 + ch * 8);
            #pragma unroll
            for (int i = 0; i < 8; ++i) Vt[kv >> 6][ch * 8 + i][kv & 63] = (ushort_t)v[i];
        }
        __syncthreads();

        #pragma unroll
        for (int sub = 0; sub < 2; ++sub) {
            const int kt = kt2 * 2 + sub;   // original 64-row tile index

            f32x16 st[2] = {};
            __builtin_amdgcn_s_setprio(1);
            #pragma unroll
            for (int t = 0; t < 2; ++t)
                #pragma unroll
                for (int m = 0; m < 4; ++m) {
                    short8 ak = *(const short8*)&Ks[sub * 64 + t * 32 + ql][m * 16 + hi * 8];
                    st[t] = MFMA32(ak, bq[m], st[t]);
                }
            __builtin_amdgcn_s_setprio(0);

            unsigned int wm0 = mrow[kt * 2]     >> (hi * 4);
            unsigned int wm1 = mrow[kt * 2 + 1] >> (hi * 4);
            float p[2][16];
            #pragma unroll
            for (int t = 0; t < 2; ++t) {
                unsigned int wt = t ? wm1 : wm0;
                #pragma unroll
                for (int r = 0; r < 16; ++r) {
                    const int rl = (r & 3) + 8 * (r >> 2);
                    float x = ((wt >> rl) & 1u) ? NEG_INF_V : st[t][r];
                    p[t][r] = EXP2(x);
                }
            }
            #pragma unroll
            for (int r = 0; r < 16; ++r) lsum16[r] += p[0][r] + p[1][r];

            unsigned int bw[4][4];
            #pragma unroll
            for (int c = 0; c < 4; ++c) {
                const int t0 = c >> 1, s0 = (2 * c) & 3, s1 = s0 + 1;
                unsigned int A = cvtpk_bf16(p[t0][4 * s0 + 0], p[t0][4 * s0 + 1]);
                unsigned int B = cvtpk_bf16(p[t0][4 * s1 + 0], p[t0][4 * s1 + 1]);
                unsigned int C = cvtpk_bf16(p[t0][4 * s0 + 2], p[t0][4 * s0 + 3]);
                unsigned int D = cvtpk_bf16(p[t0][4 * s1 + 2], p[t0][4 * s1 + 3]);
                asm volatile("v_permlane32_swap_b32 %0, %1" : "+v"(A), "+v"(B));
                asm volatile("v_permlane32_swap_b32 %0, %1" : "+v"(C), "+v"(D));
                bw[c][0] = A; bw[c][1] = C; bw[c][2] = B; bw[c][3] = D;
            }

            __builtin_amdgcn_s_setprio(1);
            #pragma unroll
            for (int c = 0; c < 4; ++c) {
                uint4 t4; t4.x = bw[c][0]; t4.y = bw[c][1]; t4.z = bw[c][2]; t4.w = bw[c][3];
                short8 bp = __builtin_bit_cast(short8, t4);
                #pragma unroll
                for (int dt = 0; dt < 2; ++dt) {
                    short8 av = *(const short8*)&Vt[sub][dt * 32 + ql][c * 16 + hi * 8];
                    oacc[dt] = MFMA32(av, bp, oacc[dt]);
                }
            }
            __builtin_amdgcn_s_setprio(0);
        }
    }

    #pragma unroll
    for (int s = 8; s; s >>= 1)
        #pragma unroll
        for (int r = 0; r < s; ++r) lsum16[r] += lsum16[r + s];
    float lsum = lsum16[0] + __shfl_xor(lsum16[0], 32);

    float inv = 1.0f / lsum;
    #pragma unroll
    for (int dt = 0; dt < 2; ++dt)
        #pragma unroll
        for (int s = 0; s < 4; ++s) {
            unsigned int lo = (unsigned int)f2bf(oacc[dt][4 * s + 0] * inv)
                            | ((unsigned int)f2bf(oacc[dt][4 * s + 1] * inv) << 16);
            unsigned int hi2 = (unsigned int)f2bf(oacc[dt][4 * s + 2] * inv)
                             | ((unsigned int)f2bf(oacc[dt][4 * s + 3] * inv) << 16);
            uint2 pk; pk.x = lo; pk.y = hi2;
            *(uint2*)(attnb + ((size_t)qrow * 4 + b) * 512 + h * 64 + dt * 32 + 8 * s + 4 * hi) = pk;
        }
}

extern "C" void kernel_launch(void* const* d_in, const int* in_sizes, int n_in,
                              void* d_out, int out_size, void* d_ws, size_t ws_size,
                              hipStream_t stream) {
    const float* utterance     = (const float*)d_in[0];
    const int*   lengths       = (const int*)d_in[1];
    const float* right_context = (const float*)d_in[2];
    const float* summary       = (const float*)d_in[3];
    const float* memory        = (const float*)d_in[4];
    const void*  mask_raw      = d_in[5];
    const float* w_q   = (const float*)d_in[6];
    const float* b_q   = (const float*)d_in[7];
    const float* w_kv  = (const float*)d_in[8];
    const float* b_kv  = (const float*)d_in[9];
    const float* w_out = (const float*)d_in[10];
    const float* b_out = (const float*)d_in[11];
    float* out = (float*)d_out;

    char* ws = (char*)d_ws;
    const size_t SZ = (size_t)NROWS * 512 * 2;             // 8.9 MB per bf16 matrix
    ushort_t* kvin   = (ushort_t*)(ws);                    // [8704][512]
    ushort_t* qin    = (ushort_t*)(ws + SZ);               // [8704][512]
    ushort_t* q_attn = (ushort_t*)(ws + 2 * SZ);           // [bh][2176][64]
    ushort_t* k_attn = (ushort_t*)(ws + 3 * SZ);
    ushort_t* v_attn = (ushort_t*)(ws + 4 * SZ);
    ushort_t* attnb  = (ushort_t*)(ws + 5 * SZ);
    ushort_t* wtq    = (ushort_t*)(ws + 6 * SZ);           // [512][512]
    ushort_t* wtkv   = wtq + (size_t)512 * 512;            // [1024][512]
    ushort_t* wtout  = wtkv + (size_t)1024 * 512;          // [512][512]
    unsigned int* mbits = (unsigned int*)(wtout + (size_t)512 * 512);  // [4][2176][68]

    // fused prep: canon bitmask + kv/q concat->bf16 + weight transposes (one launch)
    prep_kernel<<<CANON_BLKS + 2 * CONV_BLKS + TRANS_BLKS, 256, 0, stream>>>(
        mask_raw, lengths, mbits,
        memory, right_context, utterance, summary, kvin, qin,
        w_q, w_kv, w_out, wtq, wtkv, wtout);

    // unified Q + KV projection, bm-fastest dispatch, BK=64
    const float qscale = 0.125f * 1.4426950408889634f;
    proj_mfma<<<dim3(68, 12), 256, 0, stream>>>(
        qin, kvin, wtq, wtkv, b_q, b_kv, qscale,
        q_attn, k_attn, v_attn);

    // attention (544 blocks, XCD-swizzled, KVBLK=128 barrier-halving experiment)
    attn_mfma32<<<544, 256, 0, stream>>>(q_attn, k_attn, v_attn, mbits, attnb);

    // output projection + routing epilogue, BK=64
    gemm_out<<<dim3(68, 4), 256, 0, stream>>>(attnb, wtout, b_out, out);
}

// Round 19
// 151.716 us; speedup vs baseline: 1.1432x; 1.1432x over previous
//
#include <hip/hip_runtime.h>
#include <cmath>
#include <cstddef>

// Shapes (fixed): U=2048, B=4, D=512, NHEAD=8, dh=64, R=S=M=64
// Q = KV = 2176, rows = 8704
#define QLEN 2176
#define NROWS 8704
#define NEG_INF_V -100000000.0f
#define NBITW (4 * QLEN * 68)   // per-b bitmask words

#define CANON_BLKS 2312         // NBITW / 256
#define CONV_BLKS  2176         // per conv target (kv / q)
#define TRANS_BLKS 1024         // 64 x 16

typedef __attribute__((ext_vector_type(8))) short short8;
typedef __attribute__((ext_vector_type(4))) float f32x4;
typedef __attribute__((ext_vector_type(16))) float f32x16;
typedef unsigned short ushort_t;

#define MFMA16(A, B, C) __builtin_amdgcn_mfma_f32_16x16x32_bf16(A, B, C, 0, 0, 0)
#define MFMA32(A, B, C) __builtin_amdgcn_mfma_f32_32x32x16_bf16(A, B, C, 0, 0, 0)

#if __has_builtin(__builtin_amdgcn_exp2f)
#define EXP2(x) __builtin_amdgcn_exp2f(x)
#else
#define EXP2(x) __expf((x) * 0.6931471805599453f)
#endif

__device__ __forceinline__ ushort_t f2bf(float f) {
    unsigned int u = __builtin_bit_cast(unsigned int, f);
    u += 0x7FFFu + ((u >> 16) & 1u);   // RNE
    return (ushort_t)(u >> 16);
}

__device__ __forceinline__ unsigned int cvtpk_bf16(float lo, float hi) {
    unsigned int r;
    asm volatile("v_cvt_pk_bf16_f32 %0, %1, %2" : "=v"(r) : "v"(lo), "v"(hi));
    return r;
}

// async global->LDS, 16B per lane; dst must be the wave-uniform chunk base
__device__ __forceinline__ void gload16(const void* g, void* l) {
    __builtin_amdgcn_global_load_lds(
        (const __attribute__((address_space(1))) void*)g,
        (__attribute__((address_space(3))) void*)l, 16, 0, 0);
}

// ---------------- fused prep: canon | conv kv | conv q | weight transpose ------------
// block ranges: [0,2312) canon, [2312,4488) conv kvin, [4488,6664) conv qin,
// [6664,7688) transpose weights.
__global__ __launch_bounds__(256) void prep_kernel(
    const void* __restrict__ mraw, const int* __restrict__ lengths,
    unsigned int* __restrict__ bits,
    const float* __restrict__ memory, const float* __restrict__ right_context,
    const float* __restrict__ utterance, const float* __restrict__ summary,
    ushort_t* __restrict__ kvin, ushort_t* __restrict__ qin,
    const float* __restrict__ w_q, const float* __restrict__ w_kv,
    const float* __restrict__ w_out,
    ushort_t* __restrict__ wtq, ushort_t* __restrict__ wtkv, ushort_t* __restrict__ wtout)
{
    __shared__ float t[32][33];
    const int bx = blockIdx.x;
    if (bx < CANON_BLKS) {
        // inline mask-dtype detect (wave-level ballot over 4KB sample, no barrier)
        const unsigned int* mw = (const unsigned int*)mraw;
        unsigned int a123 = 0, a01 = 0, a23 = 0;
        #pragma unroll
        for (int i = 0; i < 16; ++i) {
            unsigned int wv = mw[(threadIdx.x & 63) * 16 + i];
            a123 |= wv & 0xFFFFFF00u;
            a01  |= wv & 0x0000FFFFu;
            a23  |= wv & 0xFFFF0000u;
        }
        int f;
        if (__ballot(a123 != 0) == 0)                                 f = 0;
        else if (__ballot(a01 != 0) == 0 && __ballot(a23 != 0) != 0)  f = 2;
        else                                                          f = 1;

        int idx = bx * 256 + threadIdx.x;
        if (idx >= NBITW) return;
        int b = idx / (QLEN * 68);
        int rem = idx - b * (QLEN * 68);
        int q = rem / 68, w = rem - q * 68;
        int kv0 = w * 32;
        unsigned int out = 0;
        if (f == 1) {
            const uint4* p = (const uint4*)((const unsigned char*)mraw + (size_t)q * QLEN + kv0);
            uint4 va = p[0], vb = p[1];
            unsigned int ws2[8] = {va.x, va.y, va.z, va.w, vb.x, vb.y, vb.z, vb.w};
            #pragma unroll
            for (int ww = 0; ww < 8; ++ww) {
                unsigned int x = ws2[ww];
                #pragma unroll
                for (int j = 0; j < 4; ++j)
                    out |= ((x >> (8 * j)) & 0xFFu) ? (1u << (ww * 4 + j)) : 0u;
            }
        } else {
            const uint4* p = (const uint4*)((const unsigned int*)mraw + (size_t)q * QLEN + kv0);
            #pragma unroll
            for (int g2 = 0; g2 < 8; ++g2) {
                uint4 v = p[g2];
                out |= (v.x ? 1u : 0u) << (g2 * 4);
                out |= (v.y ? 2u : 0u) << (g2 * 4);
                out |= (v.z ? 4u : 0u) << (g2 * 4);
                out |= (v.w ? 8u : 0u) << (g2 * 4);
            }
        }
        int n = (128 + lengths[b]) - kv0;   // pad: kv >= 128+lengths[b] -> masked
        unsigned int pm = (n <= 0) ? 0xFFFFFFFFu : (n >= 32 ? 0u : (0xFFFFFFFFu << n));
        bits[idx] = out | pm;
    } else if (bx < CANON_BLKS + 2 * CONV_BLKS) {
        // conv-concat f32 -> bf16; kv: [memory, right_context, utterance],
        // q: [right_context, utterance, summary]
        const bool isKV = bx < CANON_BLKS + CONV_BLKS;
        int c = (bx - (isKV ? CANON_BLKS : CANON_BLKS + CONV_BLKS)) * 256 + threadIdx.x;
        int row = c >> 6, ch = c & 63;
        if (row >= NROWS) return;
        const float* src;
        if (isKV) {
            if (row < 256)      src = memory + (size_t)row * 512;
            else if (row < 512) src = right_context + (size_t)(row - 256) * 512;
            else                src = utterance + (size_t)(row - 512) * 512;
        } else {
            if (row < 256)       src = right_context + (size_t)row * 512;
            else if (row < 8448) src = utterance + (size_t)(row - 256) * 512;
            else                 src = summary + (size_t)(row - 8448) * 512;
        }
        float4 v0 = *(const float4*)(src + ch * 8);
        float4 v1 = *(const float4*)(src + ch * 8 + 4);
        short8 o;
        o[0] = (short)f2bf(v0.x); o[1] = (short)f2bf(v0.y);
        o[2] = (short)f2bf(v0.z); o[3] = (short)f2bf(v0.w);
        o[4] = (short)f2bf(v1.x); o[5] = (short)f2bf(v1.y);
        o[6] = (short)f2bf(v1.z); o[7] = (short)f2bf(v1.w);
        ushort_t* dst = isKV ? kvin : qin;
        *(short8*)(dst + (size_t)row * 512 + ch * 8) = o;
    } else {
        // weight transpose [512][N] f32 -> [N][512] bf16
        int idx = bx - (CANON_BLKS + 2 * CONV_BLKS);
        int xb = idx & 63, yb = idx >> 6;
        const float* W; ushort_t* Wt; int N, nb;
        if (xb < 16)      { W = w_q;   Wt = wtq;   N = 512;  nb = xb; }
        else if (xb < 48) { W = w_kv;  Wt = wtkv;  N = 1024; nb = xb - 16; }
        else              { W = w_out; Wt = wtout; N = 512;  nb = xb - 48; }
        int n0 = nb * 32, k0 = yb * 32;
        int tx = threadIdx.x & 31, ty = threadIdx.x >> 5;
        #pragma unroll
        for (int i = 0; i < 4; ++i)
            t[ty + 8 * i][tx] = W[(size_t)(k0 + ty + 8 * i) * N + n0 + tx];
        __syncthreads();
        #pragma unroll
        for (int i = 0; i < 4; ++i)
            Wt[(size_t)(n0 + ty + 8 * i) * 512 + k0 + tx] = f2bf(t[tx][ty + 8 * i]);
    }
}

// ---------------- unified projection GEMM (Q + KV, uniform gload_lds A-path) ---------
// grid (68, 12): bm fastest (weight-panel L2 sharing — r15 A/B). BK=64 (r17: -2.2 us).
__global__ __launch_bounds__(256) void proj_mfma(
    const ushort_t* __restrict__ qin, const ushort_t* __restrict__ kvin,
    const ushort_t* __restrict__ wtq, const ushort_t* __restrict__ wtkv,
    const float* __restrict__ b_q, const float* __restrict__ b_kv, float qscale,
    ushort_t* __restrict__ q_attn, ushort_t* __restrict__ k_attn, ushort_t* __restrict__ v_attn)
{
    __shared__ __align__(16) ushort_t As[128][64];
    __shared__ __align__(16) ushort_t Bs[128][64];
    const int tid = threadIdx.x;
    const int wid = tid >> 6, lane = tid & 63, lr = lane & 15, lg = lane >> 4;
    const int wm = wid >> 1, wn = wid & 1;
    const int bm = blockIdx.x;
    const bool isQ = (blockIdx.y < 4);
    const int bn = isQ ? blockIdx.y : blockIdx.y - 4;
    const ushort_t* A  = isQ ? qin : kvin;
    const ushort_t* Bt = isQ ? wtq : wtkv;
    const float* bias  = isQ ? b_q : b_kv;
    const float scale  = isQ ? qscale : 1.0f;

    f32x4 acc[4][4] = {};

    for (int k0 = 0; k0 < 512; k0 += 64) {
        __syncthreads();
        #pragma unroll
        for (int i = 0; i < 4; ++i) {
            const int q = wid * 256 + 64 * i + lane;   // chunk id 0..1023
            const int row = q >> 3, pc = q & 7;
            const int sc = pc ^ (row & 7);             // content chunk at physical pc
            gload16(A + (size_t)(bm * 128 + row) * 512 + k0 + sc * 8,
                    (ushort_t*)As + (size_t)(wid * 256 + 64 * i) * 8);
            gload16(Bt + (size_t)(bn * 128 + row) * 512 + k0 + sc * 8,
                    (ushort_t*)Bs + (size_t)(wid * 256 + 64 * i) * 8);
        }
        __syncthreads();
        #pragma unroll
        for (int kk = 0; kk < 2; ++kk) {
            short8 af[4], bf[4];
            #pragma unroll
            for (int i = 0; i < 4; ++i) {
                const int ra = wm * 64 + i * 16 + lr;
                const int rb = wn * 64 + i * 16 + lr;
                af[i] = *(const short8*)&As[ra][(((kk * 4 + lg) ^ (ra & 7))) * 8];
                bf[i] = *(const short8*)&Bs[rb][(((kk * 4 + lg) ^ (rb & 7))) * 8];
            }
            #pragma unroll
            for (int i = 0; i < 4; ++i)
                #pragma unroll
                for (int j = 0; j < 4; ++j)
                    acc[i][j] = MFMA16(af[i], bf[j], acc[i][j]);
        }
    }

    // coalesced epilogue: per-wave LDS restage (same values/rounding as scatter)
    __syncthreads();
    const int gcb = bn * 128 + wn * 64;
    ushort_t* dbase; int ccb;
    if (isQ)              { dbase = q_attn; ccb = gcb >> 6; }
    else if (gcb >= 512)  { dbase = v_attn; ccb = (gcb - 512) >> 6; }
    else                  { dbase = k_attn; ccb = gcb >> 6; }
    ushort_t* Wr = ((wid & 2) ? &Bs[0][0] : &As[0][0]) + (wid & 1) * 2048;
    #pragma unroll
    for (int h = 0; h < 2; ++h) {
        #pragma unroll
        for (int ii = 0; ii < 2; ++ii) {
            const int i = h * 2 + ii;
            #pragma unroll
            for (int j = 0; j < 4; ++j) {
                const int colb = j * 16 + lr;
                const float bv = bias[gcb + colb];
                #pragma unroll
                for (int r = 0; r < 4; ++r) {
                    const int rowl = ii * 16 + lg * 4 + r;
                    const int phys = (colb >> 3) ^ (rowl & 7);
                    Wr[rowl * 64 + phys * 8 + (colb & 7)] =
                        f2bf((acc[i][j][r] + bv) * scale);
                }
            }
        }
        const int rl2 = lane >> 1;
        const int gr = bm * 128 + wm * 64 + h * 32 + rl2;
        const int q2 = gr >> 2, b2 = gr & 3;
        ushort_t* drow = dbase + (((size_t)b2 * 8 + ccb) * QLEN + q2) * 64;
        #pragma unroll
        for (int k = 0; k < 4; ++k) {
            const int ch2 = (lane & 1) * 4 + k;
            const int phys = ch2 ^ (rl2 & 7);
            *(short8*)(drow + ch2 * 8) = *(const short8*)&Wr[rl2 * 64 + phys * 8];
        }
    }
}

// ---------------- output projection GEMM + routing epilogue (BK=64) ----------
__global__ __launch_bounds__(256) void gemm_out(
    const ushort_t* __restrict__ A, const ushort_t* __restrict__ Bt,
    const float* __restrict__ bias, float* __restrict__ dstf)
{
    __shared__ __align__(16) ushort_t As[128][64];
    __shared__ __align__(16) ushort_t Bs[128][64];
    const int tid = threadIdx.x;
    const int wid = tid >> 6, lane = tid & 63, lr = lane & 15, lg = lane >> 4;
    const int wm = wid >> 1, wn = wid & 1;
    const int bm = blockIdx.x, bn = blockIdx.y;

    f32x4 acc[4][4] = {};

    for (int k0 = 0; k0 < 512; k0 += 64) {
        __syncthreads();
        #pragma unroll
        for (int i = 0; i < 4; ++i) {
            const int q = wid * 256 + 64 * i + lane;
            const int row = q >> 3, pc = q & 7;
            const int sc = pc ^ (row & 7);
            gload16(A + (size_t)(bm * 128 + row) * 512 + k0 + sc * 8,
                    (ushort_t*)As + (size_t)(wid * 256 + 64 * i) * 8);
            gload16(Bt + (size_t)(bn * 128 + row) * 512 + k0 + sc * 8,
                    (ushort_t*)Bs + (size_t)(wid * 256 + 64 * i) * 8);
        }
        __syncthreads();
        #pragma unroll
        for (int kk = 0; kk < 2; ++kk) {
            short8 af[4], bf[4];
            #pragma unroll
            for (int i = 0; i < 4; ++i) {
                const int ra = wm * 64 + i * 16 + lr;
                const int rb = wn * 64 + i * 16 + lr;
                af[i] = *(const short8*)&As[ra][(((kk * 4 + lg) ^ (ra & 7))) * 8];
                bf[i] = *(const short8*)&Bs[rb][(((kk * 4 + lg) ^ (rb & 7))) * 8];
            }
            #pragma unroll
            for (int i = 0; i < 4; ++i)
                #pragma unroll
                for (int j = 0; j < 4; ++j)
                    acc[i][j] = MFMA16(af[i], bf[j], acc[i][j]);
        }
    }

    #pragma unroll
    for (int i = 0; i < 4; ++i) {
        #pragma unroll
        for (int j = 0; j < 4; ++j) {
            int gc = bn * 128 + wn * 64 + j * 16 + lr;
            float bv = bias[gc];
            #pragma unroll
            for (int r = 0; r < 4; ++r) {
                int gr = bm * 128 + wm * 64 + i * 16 + lg * 4 + r;
                float v = acc[i][j][r] + bv;
                int q = gr >> 2, bb = gr & 3;
                if (q < 2112) {
                    dstf[(size_t)gr * 512 + gc] = v;
                } else if (q < 2175) {
                    float cv = fminf(10.0f, fmaxf(-10.0f, v));
                    dstf[(size_t)2112 * 4 * 512 + ((size_t)(q - 2112) * 4 + bb) * 512 + gc] = cv;
                } // q == 2175 dropped
            }
        }
    }
}

// ---------------- Flash attention: swapped-QK^T 32x32 MFMA, max-free exp2 softmax ----
// EXACT round-8 kernel (measured 92.5 us, VGPR 84, occ 17.8%). FROZEN — five structural
// experiments (r6 dbuf, r9 global-V^T, r10 runtime bounds, r13 gload+tr_b16, r18
// KVBLK=128) all regressed or broke via the same VGPR/occupancy cliff. Do not touch.
__global__ __launch_bounds__(256) void attn_mfma32(
    const ushort_t* __restrict__ Qa, const ushort_t* __restrict__ Ka,
    const ushort_t* __restrict__ Va,
    const unsigned int* __restrict__ mbits,   // [4][2176][68]
    ushort_t* __restrict__ attnb)             // [q*4+b][512] bf16
{
    __shared__ __align__(16) ushort_t Ks[64][72];   // [kv][dh]
    __shared__ __align__(16) ushort_t Vt[64][72];   // [dh][kv]

    // XCD-aware swizzle: 544 % 8 == 0 -> bijective
    const int swz = (blockIdx.x & 7) * 68 + (blockIdx.x >> 3);
    const int qt = swz % 17, bh = swz / 17;
    const int b = bh >> 3, h = bh & 7;
    const int tid = threadIdx.x;
    const int w = tid >> 6, lane = tid & 63;
    const int ql = lane & 31, hi = lane >> 5;
    const size_t hb = (size_t)bh * QLEN * 64;
    const int qrow = qt * 128 + w * 32 + ql;

    short8 bq[4];
    #pragma unroll
    for (int m = 0; m < 4; ++m)
        bq[m] = *(const short8*)(Qa + hb + (size_t)qrow * 64 + m * 16 + hi * 8);

    const unsigned int* mrow = mbits + ((size_t)b * QLEN + qrow) * 68;

    f32x16 oacc[2] = {};
    float lsum16[16];
    #pragma unroll
    for (int r = 0; r < 16; ++r) lsum16[r] = 0.0f;

    for (int kt = 0; kt < 34; ++kt) {
        const int k0 = kt * 64;
        __syncthreads();
        #pragma unroll
        for (int p2 = 0; p2 < 2; ++p2) {
            int c = p2 * 256 + tid;
            int row = c >> 3, ch = c & 7;
            *(short8*)&Ks[row][ch * 8] =
                *(const short8*)(Ka + hb + (size_t)(k0 + row) * 64 + ch * 8);
        }
        #pragma unroll
        for (int p2 = 0; p2 < 2; ++p2) {
            int c = p2 * 256 + tid;
            int kv = c & 63, ch = c >> 6;
            short8 v = *(const short8*)(Va + hb + (size_t)(k0 + kv) * 64 + ch * 8);
            #pragma unroll
            for (int i = 0; i < 8; ++i) Vt[ch * 8 + i][kv] = (ushort_t)v[i];
        }
        __syncthreads();

        f32x16 st[2] = {};
        __builtin_amdgcn_s_setprio(1);
        #pragma unroll
        for (int t = 0; t < 2; ++t)
            #pragma unroll
            for (int m = 0; m < 4; ++m) {
                short8 ak = *(const short8*)&Ks[t * 32 + ql][m * 16 + hi * 8];
                st[t] = MFMA32(ak, bq[m], st[t]);
            }
        __builtin_amdgcn_s_setprio(0);

        unsigned int wm0 = mrow[kt * 2]     >> (hi * 4);
        unsigned int wm1 = mrow[kt * 2 + 1] >> (hi * 4);
        float p[2][16];
        #pragma unroll
        for (int t = 0; t < 2; ++t) {
            unsigned int wt = t ? wm1 : wm0;
            #pragma unroll
            for (int r = 0; r < 16; ++r) {
                const int rl = (r & 3) + 8 * (r >> 2);
                float x = ((wt >> rl) & 1u) ? NEG_INF_V : st[t][r];
                p[t][r] = EXP2(x);
            }
        }
        #pragma unroll
        for (int r = 0; r < 16; ++r) lsum16[r] += p[0][r] + p[1][r];

        unsigned int bw[4][4];
        #pragma unroll
        for (int c = 0; c < 4; ++c) {
            const int t0 = c >> 1, s0 = (2 * c) & 3, s1 = s0 + 1;
            unsigned int A = cvtpk_bf16(p[t0][4 * s0 + 0], p[t0][4 * s0 + 1]);
            unsigned int B = cvtpk_bf16(p[t0][4 * s1 + 0], p[t0][4 * s1 + 1]);
            unsigned int C = cvtpk_bf16(p[t0][4 * s0 + 2], p[t0][4 * s0 + 3]);
            unsigned int D = cvtpk_bf16(p[t0][4 * s1 + 2], p[t0][4 * s1 + 3]);
            asm volatile("v_permlane32_swap_b32 %0, %1" : "+v"(A), "+v"(B));
            asm volatile("v_permlane32_swap_b32 %0, %1" : "+v"(C), "+v"(D));
            bw[c][0] = A; bw[c][1] = C; bw[c][2] = B; bw[c][3] = D;
        }

        __builtin_amdgcn_s_setprio(1);
        #pragma unroll
        for (int c = 0; c < 4; ++c) {
            uint4 t4; t4.x = bw[c][0]; t4.y = bw[c][1]; t4.z = bw[c][2]; t4.w = bw[c][3];
            short8 bp = __builtin_bit_cast(short8, t4);
            #pragma unroll
            for (int dt = 0; dt < 2; ++dt) {
                short8 av = *(const short8*)&Vt[dt * 32 + ql][c * 16 + hi * 8];
                oacc[dt] = MFMA32(av, bp, oacc[dt]);
            }
        }
        __builtin_amdgcn_s_setprio(0);
    }

    #pragma unroll
    for (int s = 8; s; s >>= 1)
        #pragma unroll
        for (int r = 0; r < s; ++r) lsum16[r] += lsum16[r + s];
    float lsum = lsum16[0] + __shfl_xor(lsum16[0], 32);

    float inv = 1.0f / lsum;
    #pragma unroll
    for (int dt = 0; dt < 2; ++dt)
        #pragma unroll
        for (int s = 0; s < 4; ++s) {
            unsigned int lo = (unsigned int)f2bf(oacc[dt][4 * s + 0] * inv)
                            | ((unsigned int)f2bf(oacc[dt][4 * s + 1] * inv) << 16);
            unsigned int hi2 = (unsigned int)f2bf(oacc[dt][4 * s + 2] * inv)
                             | ((unsigned int)f2bf(oacc[dt][4 * s + 3] * inv) << 16);
            uint2 pk; pk.x = lo; pk.y = hi2;
            *(uint2*)(attnb + ((size_t)qrow * 4 + b) * 512 + h * 64 + dt * 32 + 8 * s + 4 * hi) = pk;
        }
}

extern "C" void kernel_launch(void* const* d_in, const int* in_sizes, int n_in,
                              void* d_out, int out_size, void* d_ws, size_t ws_size,
                              hipStream_t stream) {
    const float* utterance     = (const float*)d_in[0];
    const int*   lengths       = (const int*)d_in[1];
    const float* right_context = (const float*)d_in[2];
    const float* summary       = (const float*)d_in[3];
    const float* memory        = (const float*)d_in[4];
    const void*  mask_raw      = d_in[5];
    const float* w_q   = (const float*)d_in[6];
    const float* b_q   = (const float*)d_in[7];
    const float* w_kv  = (const float*)d_in[8];
    const float* b_kv  = (const float*)d_in[9];
    const float* w_out = (const float*)d_in[10];
    const float* b_out = (const float*)d_in[11];
    float* out = (float*)d_out;

    char* ws = (char*)d_ws;
    const size_t SZ = (size_t)NROWS * 512 * 2;             // 8.9 MB per bf16 matrix
    ushort_t* kvin   = (ushort_t*)(ws);                    // [8704][512]
    ushort_t* qin    = (ushort_t*)(ws + SZ);               // [8704][512]
    ushort_t* q_attn = (ushort_t*)(ws + 2 * SZ);           // [bh][2176][64]
    ushort_t* k_attn = (ushort_t*)(ws + 3 * SZ);
    ushort_t* v_attn = (ushort_t*)(ws + 4 * SZ);
    ushort_t* attnb  = (ushort_t*)(ws + 5 * SZ);
    ushort_t* wtq    = (ushort_t*)(ws + 6 * SZ);           // [512][512]
    ushort_t* wtkv   = wtq + (size_t)512 * 512;            // [1024][512]
    ushort_t* wtout  = wtkv + (size_t)1024 * 512;          // [512][512]
    unsigned int* mbits = (unsigned int*)(wtout + (size_t)512 * 512);  // [4][2176][68]

    // fused prep: canon bitmask + kv/q concat->bf16 + weight transposes (one launch)
    prep_kernel<<<CANON_BLKS + 2 * CONV_BLKS + TRANS_BLKS, 256, 0, stream>>>(
        mask_raw, lengths, mbits,
        memory, right_context, utterance, summary, kvin, qin,
        w_q, w_kv, w_out, wtq, wtkv, wtout);

    // unified Q + KV projection, bm-fastest dispatch, BK=64
    const float qscale = 0.125f * 1.4426950408889634f;
    proj_mfma<<<dim3(68, 12), 256, 0, stream>>>(
        qin, kvin, wtq, wtkv, b_q, b_kv, qscale,
        q_attn, k_attn, v_attn);

    // attention (544 blocks, XCD-swizzled, frozen r8 kernel)
    attn_mfma32<<<544, 256, 0, stream>>>(q_attn, k_attn, v_attn, mbits, attnb);

    // output projection + routing epilogue, BK=64
    gemm_out<<<dim3(68, 4), 256, 0, stream>>>(attnb, wtout, b_out, out);
}